// Round 3
// baseline (513.607 us; speedup 1.0000x reference)
//
#include <hip/hip_runtime.h>
#include <math.h>

// Problem constants: B=2,S=1024 -> T=2048 tokens; H=1024; I=2048; E=8; TOP_K=2
#define T_TOK 2048
#define H_DIM 1024
#define I_DIM 2048
#define NEXP  8

typedef _Float16 f16x8 __attribute__((ext_vector_type(8)));
typedef _Float16 f16x4 __attribute__((ext_vector_type(4)));
typedef float    f32x4 __attribute__((ext_vector_type(4)));

// ---------------------------------------------------------------------------
// async 16B global->LDS copy. LDS dest = WAVE-UNIFORM base + lane*16.
// ---------------------------------------------------------------------------
__device__ __forceinline__ void cp16(const void* g, void* l) {
  __builtin_amdgcn_global_load_lds(
      (const __attribute__((address_space(1))) void*)g,
      (__attribute__((address_space(3))) void*)l, 16, 0, 0);
}

// ---------------------------------------------------------------------------
// fp32 -> f16 streaming convert. n divisible by 1024.
// ---------------------------------------------------------------------------
__global__ __launch_bounds__(256) void cvt_f16_kernel(
    const float* __restrict__ in, _Float16* __restrict__ hi, int n) {
  int i = (blockIdx.x * 256 + threadIdx.x) * 4;
  if (i >= n) return;
  float4 v = *(const float4*)(in + i);
  f16x4 hv = {(_Float16)v.x, (_Float16)v.y, (_Float16)v.z, (_Float16)v.w};
  *(f16x4*)(hi + i) = hv;
}

// ---------------------------------------------------------------------------
// Router: logits = x @ gw^T, softmax, top-2, normalized weights. 1 wave/token.
// ---------------------------------------------------------------------------
__global__ __launch_bounds__(64) void router_kernel(
    const float* __restrict__ x, const float* __restrict__ gw,
    int* __restrict__ topIdx, float* __restrict__ topW) {
  int t = blockIdx.x;
  int lane = threadIdx.x;
  float p[NEXP];
#pragma unroll
  for (int e = 0; e < NEXP; ++e) p[e] = 0.f;
  const float* xr = x + (size_t)t * H_DIM;
  for (int h = lane; h < H_DIM; h += 64) {
    float xv = xr[h];
#pragma unroll
    for (int e = 0; e < NEXP; ++e) p[e] += xv * gw[e * H_DIM + h];
  }
#pragma unroll
  for (int e = 0; e < NEXP; ++e) {
    float v = p[e];
    for (int off = 32; off > 0; off >>= 1) v += __shfl_down(v, off);
    p[e] = v;
  }
  if (lane == 0) {
    float mx = p[0];
#pragma unroll
    for (int e = 1; e < NEXP; ++e) mx = fmaxf(mx, p[e]);
    float ex[NEXP], s = 0.f;
#pragma unroll
    for (int e = 0; e < NEXP; ++e) { ex[e] = expf(p[e] - mx); s += ex[e]; }
#pragma unroll
    for (int e = 0; e < NEXP; ++e) ex[e] /= s;
    int i0 = 0; float v0 = ex[0];
#pragma unroll
    for (int e = 1; e < NEXP; ++e) if (ex[e] > v0) { v0 = ex[e]; i0 = e; }
    int i1 = -1; float v1 = -1.f;
#pragma unroll
    for (int e = 0; e < NEXP; ++e) if (e != i0 && ex[e] > v1) { v1 = ex[e]; i1 = e; }
    float sum = fmaxf(v0 + v1, 1e-12f);
    topIdx[2 * t] = i0;  topIdx[2 * t + 1] = i1;
    topW[2 * t] = v0 / sum;  topW[2 * t + 1] = v1 / sum;
  }
}

// ---------------------------------------------------------------------------
// Fused gate+up GEMM, BK=64, all experts via gridDim.z, ALL-cp16 staging.
// inter[e][t][i] = silu(x@Wg^T) * (x@Wu^T), stored f16.
// GRID: x = N-tile, y = M-tile, z = expert. 128x128 tile, BK=64, 4 waves 2x2.
// LDS 48KB: A [0,16K) | Bg [16K,32K) | Bu [32K,48K).
// Swizzle: LDS chunk s of row r holds global k-chunk s ^ (r&7)  (conflict-free,
// measured SQ_LDS_BANK_CONFLICT = 0).
// ---------------------------------------------------------------------------
__global__ __launch_bounds__(256, 2) void gemm_gateup(
    const _Float16* __restrict__ xHi, const _Float16* __restrict__ gup16,
    _Float16* __restrict__ intHi) {
  __shared__ _Float16 lds[24576];  // 48 KB

  const int tid = threadIdx.x;
  const int wave = tid >> 6, lane = tid & 63;
  const int rowA0 = blockIdx.y * 128;  // M tile
  const int colB0 = blockIdx.x * 128;  // N tile within I
  const int e = blockIdx.z;

  // staging coords
  const int sr = lane >> 3;            // row within 8-row slice
  const int sc = lane & 7;             // LDS chunk
  const int gcol = (sc ^ sr) * 8;      // global k-offset (f16 elems), const/thread
  const int rbase = wave * 8 + sr;

  const int wm = wave >> 1, wn = wave & 1;
  const int fr = lane & 15;
  const int quad = lane >> 4;

  f32x4 accG[4][4], accU[4][4];
#pragma unroll
  for (int i = 0; i < 4; ++i)
#pragma unroll
    for (int j = 0; j < 4; ++j) {
      accG[i][j] = (f32x4){0.f, 0.f, 0.f, 0.f};
      accU[i][j] = (f32x4){0.f, 0.f, 0.f, 0.f};
    }

  const _Float16* gupG = gup16 + ((size_t)e * 2 * I_DIM + colB0) * H_DIM;
  const _Float16* gupU = gupG + (size_t)I_DIM * H_DIM;
  char* ldsB = (char*)lds;

  for (int k0 = 0; k0 < H_DIM; k0 += 64) {
    const int kcol = k0 + gcol;
#pragma unroll
    for (int i = 0; i < 4; ++i) {
      const int row = i * 32 + rbase;
      const unsigned dst = (unsigned)(i * 4096 + wave * 1024);
      cp16(xHi  + (size_t)(rowA0 + row) * H_DIM + kcol, ldsB + dst);
      cp16(gupG + (size_t)row * H_DIM + kcol, ldsB + 16384u + dst);
      cp16(gupU + (size_t)row * H_DIM + kcol, ldsB + 32768u + dst);
    }
    __syncthreads();

#pragma unroll
    for (int kk = 0; kk < 2; ++kk) {
      f16x8 ah[4];
#pragma unroll
      for (int i = 0; i < 4; ++i) {
        const int row = wm * 64 + i * 16 + fr;
        ah[i] = *(const f16x8*)&lds[row * 64 + (((kk * 4 + quad) ^ (fr & 7)) * 8)];
      }
#pragma unroll
      for (int j = 0; j < 4; ++j) {
        const int row = wn * 64 + j * 16 + fr;
        const int boff = row * 64 + (((kk * 4 + quad) ^ (fr & 7)) * 8);
        f16x8 bg = *(const f16x8*)&lds[8192 + boff];
        f16x8 bu = *(const f16x8*)&lds[16384 + boff];
#pragma unroll
        for (int i = 0; i < 4; ++i) {
          accG[i][j] = __builtin_amdgcn_mfma_f32_16x16x32_f16(ah[i], bg, accG[i][j], 0, 0, 0);
          accU[i][j] = __builtin_amdgcn_mfma_f32_16x16x32_f16(ah[i], bu, accU[i][j], 0, 0, 0);
        }
      }
    }
    __syncthreads();
  }

  // epilogue: C/D layout col=lane&15, row=quad*4+reg. inter = silu(g)*u -> f16
  const int er = quad * 4;
  const int ec = lane & 15;
#pragma unroll
  for (int i = 0; i < 4; ++i)
#pragma unroll
    for (int j = 0; j < 4; ++j) {
      const int row = rowA0 + wm * 64 + i * 16 + er;
      const int col = colB0 + wn * 64 + j * 16 + ec;
#pragma unroll
      for (int r = 0; r < 4; ++r) {
        float g = accG[i][j][r], u = accU[i][j][r];
        float val = g / (1.f + __expf(-g)) * u;
        intHi[((size_t)e * T_TOK + row + r) * I_DIM + col] = (_Float16)val;
      }
    }
}

// ---------------------------------------------------------------------------
// Down GEMM, 256x256 tile, BK=64, 8 waves (2M x 4N), double-buffered LDS with
// issue-early staging (2-phase pipeline, T3-lite):
//   prologue: stage tile0 -> buf0; syncthreads (drain)
//   iter t:   stage tile t+1 -> buf[cur^1]  (8 cp16, issued FIRST)
//             compute 64 MFMA/wave from buf[cur] (setprio around MFMA)
//             __syncthreads()  == vmcnt(0)+lgkmcnt(0)+barrier: exactly the
//             wait needed (tile t+1 landed; all waves done reading cur).
// Race-free: only cross-wave deps are at iteration boundaries.
// eo[e][t][h] (f16) = inter @ wd16^T.  M=T(2048), N=H(1024), K=I(2048).
// GRID: x = M-tile(8), y = N-tile(4), z = expert(8) -> 256 blocks = 1/CU.
// Same-A blocks (vary y) have ids differing by 8 -> same XCD -> A-slab reuse.
// LDS 128KB: buf0 {A 256x64 @0, B 256x64 @32K} buf1 @64K.
// Row = 64 f16 = 128B = 8 chunks; chunk slot s of row r holds global chunk
// s ^ (r&7)  (conflict-free, measured 0).
// Staging: slice = 64 rows; wave w covers rows w*8..w*8+7 of each slice,
// lane: row += lane>>3, chunk = lane&7 (cp16 dest = wave base + lane*16).
// ---------------------------------------------------------------------------
__global__ __launch_bounds__(512, 2) void gemm_down(
    const _Float16* __restrict__ intHi, const _Float16* __restrict__ wd16,
    _Float16* __restrict__ eo) {
  __shared__ _Float16 lds[65536];  // 128 KB

  const int tid = threadIdx.x;
  const int wave = tid >> 6, lane = tid & 63;
  const int rowA0 = blockIdx.x * 256;
  const int colB0 = blockIdx.y * 256;
  const int e = blockIdx.z;

  // staging coords
  const int sr = lane >> 3;             // row within 8-row wave stripe
  const int sc = lane & 7;              // LDS chunk slot
  const int gcol = (sc ^ sr) * 8;       // global k-offset (f16 elems)

  // compute coords: 8 waves = 2M x 4N; per-wave out 128 rows x 64 cols
  const int wm = wave >> 2;             // 0..1
  const int wn = wave & 3;              // 0..3
  const int fr = lane & 15;
  const int quad = lane >> 4;

  f32x4 acc[8][4];
#pragma unroll
  for (int i = 0; i < 8; ++i)
#pragma unroll
    for (int j = 0; j < 4; ++j) acc[i][j] = (f32x4){0.f, 0.f, 0.f, 0.f};

  // per-thread global staging bases (row fixed; k advances by 64/tile)
  const _Float16* aSrc = intHi + (size_t)e * T_TOK * I_DIM +
                         (size_t)(rowA0 + wave * 8 + sr) * I_DIM + gcol;
  const _Float16* bSrc = wd16 + ((size_t)e * H_DIM + colB0 + wave * 8 + sr) * I_DIM + gcol;
  char* ldsB = (char*)lds;
  char* ldsAw = ldsB + wave * 1024u;            // wave's 8-row stripe (8*128B)
  char* ldsBw = ldsAw + 32768u;                 // B tile at +32KB

  const int NT = I_DIM / 64;  // 32 K-tiles

  // prologue: stage tile 0 into buf0
#pragma unroll
  for (int s = 0; s < 4; ++s) {
    cp16(aSrc + (size_t)s * 64 * I_DIM, ldsAw + s * 8192u);
    cp16(bSrc + (size_t)s * 64 * I_DIM, ldsBw + s * 8192u);
  }
  __syncthreads();

  for (int t = 0; t < NT; ++t) {
    const int cur = t & 1;
    // issue-early: stage tile t+1 into the other buffer (front-loaded)
    if (t < NT - 1) {
      const unsigned nb = (unsigned)((cur ^ 1) * 65536u);
      const _Float16* aS = aSrc + (size_t)(t + 1) * 64;
      const _Float16* bS = bSrc + (size_t)(t + 1) * 64;
#pragma unroll
      for (int s = 0; s < 4; ++s) {
        cp16(aS + (size_t)s * 64 * I_DIM, ldsAw + nb + s * 8192u);
        cp16(bS + (size_t)s * 64 * I_DIM, ldsBw + nb + s * 8192u);
      }
    }
    // compute tile t from buf[cur]
    const int cb = cur * 32768;  // f16 elems
#pragma unroll
    for (int ks = 0; ks < 2; ++ks) {
      const int ksl = (ks * 4 + quad);
      f16x8 bh[4];
#pragma unroll
      for (int j = 0; j < 4; ++j) {
        const int row = wn * 64 + j * 16 + fr;
        bh[j] = *(const f16x8*)&lds[cb + 16384 + row * 64 + ((ksl ^ (fr & 7)) * 8)];
      }
      f16x8 ah[8];
#pragma unroll
      for (int i = 0; i < 8; ++i) {
        const int row = wm * 128 + i * 16 + fr;
        ah[i] = *(const f16x8*)&lds[cb + row * 64 + ((ksl ^ (fr & 7)) * 8)];
      }
      __builtin_amdgcn_s_setprio(1);
#pragma unroll
      for (int j = 0; j < 4; ++j)
#pragma unroll
        for (int i = 0; i < 8; ++i)
          acc[i][j] = __builtin_amdgcn_mfma_f32_16x16x32_f16(ah[i], bh[j], acc[i][j], 0, 0, 0);
      __builtin_amdgcn_s_setprio(0);
    }
    __syncthreads();  // vmcnt(0)+lgkmcnt(0)+barrier: t+1 landed, cur consumed
  }

  // epilogue: C/D layout col=lane&15, row=quad*4+reg
  const int er = quad * 4;
  const int ec = lane & 15;
#pragma unroll
  for (int i = 0; i < 8; ++i)
#pragma unroll
    for (int j = 0; j < 4; ++j) {
      const int row = rowA0 + wm * 128 + i * 16 + er;
      const int col = colB0 + wn * 64 + j * 16 + ec;
#pragma unroll
      for (int r = 0; r < 4; ++r)
        eo[((size_t)e * T_TOK + row + r) * H_DIM + col] = (_Float16)acc[i][j][r];
    }
}

// ---------------------------------------------------------------------------
// Gram: gram36[p] = sum_j eo[a][j]*eo[b][j] for pairs a<=b.
// ---------------------------------------------------------------------------
__global__ __launch_bounds__(256) void gram_kernel(
    const _Float16* __restrict__ eo, float* __restrict__ gram) {
  float s[36];
#pragma unroll
  for (int p = 0; p < 36; ++p) s[p] = 0.f;
  const size_t total = (size_t)T_TOK * H_DIM;
  const size_t stride = (size_t)gridDim.x * 256;
  for (size_t j = (size_t)blockIdx.x * 256 + threadIdx.x; j < total; j += stride) {
    float v[NEXP];
#pragma unroll
    for (int e = 0; e < NEXP; ++e) v[e] = (float)eo[(size_t)e * total + j];
    int p = 0;
#pragma unroll
    for (int a = 0; a < NEXP; ++a)
#pragma unroll
      for (int b = a; b < NEXP; ++b) { s[p] += v[a] * v[b]; ++p; }
  }
#pragma unroll
  for (int p = 0; p < 36; ++p) {
    float v = s[p];
    for (int off = 32; off > 0; off >>= 1) v += __shfl_down(v, off);
    s[p] = v;
  }
  __shared__ float red[4][36];
  const int wave = threadIdx.x >> 6, lane = threadIdx.x & 63;
  if (lane == 0)
#pragma unroll
    for (int p = 0; p < 36; ++p) red[wave][p] = s[p];
  __syncthreads();
  if (threadIdx.x < 36) {
    float v = red[0][threadIdx.x] + red[1][threadIdx.x] + red[2][threadIdx.x] + red[3][threadIdx.x];
    atomicAdd(&gram[threadIdx.x], v);
  }
}

// ---------------------------------------------------------------------------
// Sim: 8x8 similarity from gram36.
// ---------------------------------------------------------------------------
__global__ __launch_bounds__(64) void sim_kernel(
    const float* __restrict__ gram, float* __restrict__ simOut) {
  const int t = threadIdx.x;
  const int e1 = t >> 3, e2 = t & 7;
  int a = e1 < e2 ? e1 : e2;
  int b = e1 < e2 ? e2 : e1;
  const float g = gram[a * 8 - a * (a - 1) / 2 + (b - a)];
  const float sq1 = gram[e1 * 8 - e1 * (e1 - 1) / 2];
  const float sq2 = gram[e2 * 8 - e2 * (e2 - 1) / 2];
  float d2 = fmaxf(sq1 + sq2 - 2.f * g, 0.f);
  float dist = (e1 == e2) ? 0.f : sqrtf(d2);
  float dmax = dist;
  for (int off = 32; off > 0; off >>= 1) dmax = fmaxf(dmax, __shfl_xor(dmax, off));
  float sim = 1.f - dist / fmaxf(dmax, 1e-12f);
  if (e1 == e2) sim = 1.f;
  simOut[t] = sim;
}

// ---------------------------------------------------------------------------
// Final: out[t] = w0*eo[i0][t] + w1*eo[i1][t]. One block per token.
// ---------------------------------------------------------------------------
__global__ __launch_bounds__(256) void final_kernel(
    const _Float16* __restrict__ eo, const int* __restrict__ topIdx,
    const float* __restrict__ topW, float* __restrict__ out) {
  const int t = blockIdx.x;
  const int c = threadIdx.x * 4;
  const int i0 = topIdx[2 * t], i1 = topIdx[2 * t + 1];
  const float w0 = topW[2 * t], w1 = topW[2 * t + 1];
  const size_t per = (size_t)T_TOK * H_DIM;
  f16x4 a = *(const f16x4*)&eo[(size_t)i0 * per + (size_t)t * H_DIM + c];
  f16x4 b = *(const f16x4*)&eo[(size_t)i1 * per + (size_t)t * H_DIM + c];
  float4 r;
  r.x = w0 * (float)a[0] + w1 * (float)b[0];
  r.y = w0 * (float)a[1] + w1 * (float)b[1];
  r.z = w0 * (float)a[2] + w1 * (float)b[2];
  r.w = w0 * (float)a[3] + w1 * (float)b[3];
  *(float4*)&out[(size_t)t * H_DIM + c] = r;
}

// ---------------------------------------------------------------------------
// Workspace layout (bytes), total 132 MiB + 48 KiB, via liveness aliasing:
//  xHi @0 (4 MiB) | intHi @4 MiB (64 MiB)
//  gup16 @68 MiB (64 MiB, live only until gemm_gateup completes)
//  wd16 @68 MiB (32 MiB, written AFTER gateup -- stream-ordered)
//  eo   @100 MiB (32 MiB)
//  topIdx @132 MiB | topW +16K | gram +32K
// ---------------------------------------------------------------------------
extern "C" void kernel_launch(void* const* d_in, const int* in_sizes, int n_in,
                              void* d_out, int out_size, void* d_ws, size_t ws_size,
                              hipStream_t stream) {
  (void)in_sizes; (void)n_in; (void)out_size; (void)ws_size;
  const float* x   = (const float*)d_in[0];  // (2,1024,1024)
  const float* gw  = (const float*)d_in[1];  // (8,1024)
  const float* gup = (const float*)d_in[2];  // (8,4096,1024)
  const float* dwn = (const float*)d_in[3];  // (8,1024,2048)
  float* out = (float*)d_out;                // final (2M) ++ sim (64)

  char* ws = (char*)d_ws;
  const size_t MB = 1u << 20;
  _Float16* xHi    = (_Float16*)(ws + 0 * MB);
  _Float16* intHi  = (_Float16*)(ws + 4 * MB);
  _Float16* gup16  = (_Float16*)(ws + 68 * MB);   // dead after gemm_gateup
  _Float16* wd16   = (_Float16*)(ws + 68 * MB);   // born after gemm_gateup
  _Float16* eo     = (_Float16*)(ws + 100 * MB);
  int*      topIdx = (int*)(ws + 132 * MB);
  float*    topW   = (float*)(ws + 132 * MB + 16384);
  float*    gram   = (float*)(ws + 132 * MB + 32768);

  cvt_f16_kernel<<<2048, 256, 0, stream>>>(x, xHi, T_TOK * H_DIM);
  cvt_f16_kernel<<<32768, 256, 0, stream>>>(gup, gup16, NEXP * 2 * I_DIM * H_DIM);
  router_kernel<<<T_TOK, 64, 0, stream>>>(x, gw, topIdx, topW);
  hipMemsetAsync(gram, 0, 36 * sizeof(float), stream);

  // gate+up fused: grid x=N (B-tiles XCD-co-located), y=M, z=E
  gemm_gateup<<<dim3(I_DIM / 128, T_TOK / 128, NEXP), 256, 0, stream>>>(
      xHi, gup16, intHi);

  // dwn -> f16 AFTER gateup (wd16 aliases gup16's region; stream-ordered)
  cvt_f16_kernel<<<16384, 256, 0, stream>>>(dwn, wd16, NEXP * H_DIM * I_DIM);

  // down: 256x256 tiles, grid x=M (A-slabs XCD-co-located), y=N, z=E
  gemm_down<<<dim3(T_TOK / 256, H_DIM / 256, NEXP), 512, 0, stream>>>(
      intHi, wd16, eo);

  gram_kernel<<<2048, 256, 0, stream>>>(eo, gram);
  sim_kernel<<<1, 64, 0, stream>>>(gram, out + (size_t)T_TOK * H_DIM);
  final_kernel<<<T_TOK, 256, 0, stream>>>(eo, topIdx, topW, out);
}

// Round 4
// 499.263 us; speedup vs baseline: 1.0287x; 1.0287x over previous
//
#include <hip/hip_runtime.h>
#include <math.h>

// Problem constants: B=2,S=1024 -> T=2048 tokens; H=1024; I=2048; E=8; TOP_K=2
#define T_TOK 2048
#define H_DIM 1024
#define I_DIM 2048
#define NEXP  8

typedef _Float16 f16x8 __attribute__((ext_vector_type(8)));
typedef _Float16 f16x4 __attribute__((ext_vector_type(4)));
typedef float    f32x4 __attribute__((ext_vector_type(4)));

// ---------------------------------------------------------------------------
// async 16B global->LDS copy. LDS dest = WAVE-UNIFORM base + lane*16.
// ---------------------------------------------------------------------------
__device__ __forceinline__ void cp16(const void* g, void* l) {
  __builtin_amdgcn_global_load_lds(
      (const __attribute__((address_space(1))) void*)g,
      (__attribute__((address_space(3))) void*)l, 16, 0, 0);
}

// ---------------------------------------------------------------------------
// fp32 -> f16 streaming convert (standalone; used for dwn when ws is small).
// ---------------------------------------------------------------------------
__global__ __launch_bounds__(256) void cvt_f16_kernel(
    const float* __restrict__ in, _Float16* __restrict__ hi, int n) {
  int i = (blockIdx.x * 256 + threadIdx.x) * 4;
  if (i >= n) return;
  float4 v = *(const float4*)(in + i);
  f16x4 hv = {(_Float16)v.x, (_Float16)v.y, (_Float16)v.z, (_Float16)v.w};
  *(f16x4*)(hi + i) = hv;
}

// ---------------------------------------------------------------------------
// PREP (fused): router + gram-zero + cvt x + cvt gup [+ cvt dwn if doDwn].
// Grid layout (256-thr blocks):
//   [0,512)            router: 4 tokens/block, one per wave; block 0 lanes<36
//                      also zero gram.
//   [512, 2560)        cvt x    (2M elems, 1024/block)
//   [2560, 35328)      cvt gup  (33.5M elems)
//   [35328, 35328+16K) cvt dwn  (16.8M elems) -- only when doDwn
// Router first: latency-bound blocks start early, hide under streaming cvt.
// ---------------------------------------------------------------------------
__global__ __launch_bounds__(256) void prep_kernel(
    const float* __restrict__ x, _Float16* __restrict__ xHi,
    const float* __restrict__ gup, _Float16* __restrict__ gup16,
    const float* __restrict__ dwn, _Float16* __restrict__ wd16,
    const float* __restrict__ gw,
    int* __restrict__ topIdx, float* __restrict__ topW,
    float* __restrict__ gram) {
  const int b = blockIdx.x;
  const int tid = threadIdx.x;

  if (b < 512) {
    // ---- router (one token per wave) + gram zero ----
    if (b == 0 && tid < 36) gram[tid] = 0.f;
    const int wave = tid >> 6, lane = tid & 63;
    const int t = b * 4 + wave;
    float p[NEXP];
#pragma unroll
    for (int e = 0; e < NEXP; ++e) p[e] = 0.f;
    const float* xr = x + (size_t)t * H_DIM;
    for (int h = lane; h < H_DIM; h += 64) {
      float xv = xr[h];
#pragma unroll
      for (int e = 0; e < NEXP; ++e) p[e] += xv * gw[e * H_DIM + h];
    }
#pragma unroll
    for (int e = 0; e < NEXP; ++e) {
      float v = p[e];
      for (int off = 32; off > 0; off >>= 1) v += __shfl_down(v, off);
      p[e] = v;
    }
    if (lane == 0) {
      float mx = p[0];
#pragma unroll
      for (int e = 1; e < NEXP; ++e) mx = fmaxf(mx, p[e]);
      float ex[NEXP], s = 0.f;
#pragma unroll
      for (int e = 0; e < NEXP; ++e) { ex[e] = expf(p[e] - mx); s += ex[e]; }
#pragma unroll
      for (int e = 0; e < NEXP; ++e) ex[e] /= s;
      int i0 = 0; float v0 = ex[0];
#pragma unroll
      for (int e = 1; e < NEXP; ++e) if (ex[e] > v0) { v0 = ex[e]; i0 = e; }
      int i1 = -1; float v1 = -1.f;
#pragma unroll
      for (int e = 0; e < NEXP; ++e) if (e != i0 && ex[e] > v1) { v1 = ex[e]; i1 = e; }
      float sum = fmaxf(v0 + v1, 1e-12f);
      topIdx[2 * t] = i0;  topIdx[2 * t + 1] = i1;
      topW[2 * t] = v0 / sum;  topW[2 * t + 1] = v1 / sum;
    }
    return;
  }

  // ---- streaming fp32 -> f16 converts ----
  int rb = b - 512;
  const float* src;
  _Float16* dst;
  if (rb < 2048) {
    src = x;  dst = xHi;
  } else if (rb < 2048 + 32768) {
    rb -= 2048;  src = gup;  dst = gup16;
  } else {
    rb -= (2048 + 32768);  src = dwn;  dst = wd16;
  }
  const size_t i = (size_t)rb * 1024 + (size_t)tid * 4;
  float4 v = *(const float4*)(src + i);
  f16x4 hv = {(_Float16)v.x, (_Float16)v.y, (_Float16)v.z, (_Float16)v.w};
  *(f16x4*)(dst + i) = hv;
}

// ---------------------------------------------------------------------------
// Fused gate+up GEMM, BK=64, all experts via gridDim.z, ALL-cp16 staging.
// inter[e][t][i] = silu(x@Wg^T) * (x@Wu^T), stored f16.
// GRID: x = N-tile, y = M-tile, z = expert. 128x128 tile, BK=64, 4 waves 2x2.
// LDS 48KB: A [0,16K) | Bg [16K,32K) | Bu [32K,48K).
// Swizzle: LDS chunk s of row r holds global k-chunk s ^ (r&7)  (conflict-free,
// measured SQ_LDS_BANK_CONFLICT = 0).
// ---------------------------------------------------------------------------
__global__ __launch_bounds__(256, 2) void gemm_gateup(
    const _Float16* __restrict__ xHi, const _Float16* __restrict__ gup16,
    _Float16* __restrict__ intHi) {
  __shared__ _Float16 lds[24576];  // 48 KB

  const int tid = threadIdx.x;
  const int wave = tid >> 6, lane = tid & 63;
  const int rowA0 = blockIdx.y * 128;  // M tile
  const int colB0 = blockIdx.x * 128;  // N tile within I
  const int e = blockIdx.z;

  // staging coords
  const int sr = lane >> 3;            // row within 8-row slice
  const int sc = lane & 7;             // LDS chunk
  const int gcol = (sc ^ sr) * 8;      // global k-offset (f16 elems), const/thread
  const int rbase = wave * 8 + sr;

  const int wm = wave >> 1, wn = wave & 1;
  const int fr = lane & 15;
  const int quad = lane >> 4;

  f32x4 accG[4][4], accU[4][4];
#pragma unroll
  for (int i = 0; i < 4; ++i)
#pragma unroll
    for (int j = 0; j < 4; ++j) {
      accG[i][j] = (f32x4){0.f, 0.f, 0.f, 0.f};
      accU[i][j] = (f32x4){0.f, 0.f, 0.f, 0.f};
    }

  const _Float16* gupG = gup16 + ((size_t)e * 2 * I_DIM + colB0) * H_DIM;
  const _Float16* gupU = gupG + (size_t)I_DIM * H_DIM;
  char* ldsB = (char*)lds;

  for (int k0 = 0; k0 < H_DIM; k0 += 64) {
    const int kcol = k0 + gcol;
#pragma unroll
    for (int i = 0; i < 4; ++i) {
      const int row = i * 32 + rbase;
      const unsigned dst = (unsigned)(i * 4096 + wave * 1024);
      cp16(xHi  + (size_t)(rowA0 + row) * H_DIM + kcol, ldsB + dst);
      cp16(gupG + (size_t)row * H_DIM + kcol, ldsB + 16384u + dst);
      cp16(gupU + (size_t)row * H_DIM + kcol, ldsB + 32768u + dst);
    }
    __syncthreads();

#pragma unroll
    for (int kk = 0; kk < 2; ++kk) {
      f16x8 ah[4];
#pragma unroll
      for (int i = 0; i < 4; ++i) {
        const int row = wm * 64 + i * 16 + fr;
        ah[i] = *(const f16x8*)&lds[row * 64 + (((kk * 4 + quad) ^ (fr & 7)) * 8)];
      }
#pragma unroll
      for (int j = 0; j < 4; ++j) {
        const int row = wn * 64 + j * 16 + fr;
        const int boff = row * 64 + (((kk * 4 + quad) ^ (fr & 7)) * 8);
        f16x8 bg = *(const f16x8*)&lds[8192 + boff];
        f16x8 bu = *(const f16x8*)&lds[16384 + boff];
#pragma unroll
        for (int i = 0; i < 4; ++i) {
          accG[i][j] = __builtin_amdgcn_mfma_f32_16x16x32_f16(ah[i], bg, accG[i][j], 0, 0, 0);
          accU[i][j] = __builtin_amdgcn_mfma_f32_16x16x32_f16(ah[i], bu, accU[i][j], 0, 0, 0);
        }
      }
    }
    __syncthreads();
  }

  // epilogue: C/D layout col=lane&15, row=quad*4+reg. inter = silu(g)*u -> f16
  const int er = quad * 4;
  const int ec = lane & 15;
#pragma unroll
  for (int i = 0; i < 4; ++i)
#pragma unroll
    for (int j = 0; j < 4; ++j) {
      const int row = rowA0 + wm * 64 + i * 16 + er;
      const int col = colB0 + wn * 64 + j * 16 + ec;
#pragma unroll
      for (int r = 0; r < 4; ++r) {
        float g = accG[i][j][r], u = accU[i][j][r];
        float val = g / (1.f + __expf(-g)) * u;
        intHi[((size_t)e * T_TOK + row + r) * I_DIM + col] = (_Float16)val;
      }
    }
}

// ---------------------------------------------------------------------------
// Down GEMM, 256x256 tile, BK=64, 8 waves (2M x 4N), double-buffered LDS with
// issue-early staging. eo[e][t][h] (f16) = inter @ wd16^T.
// GRID: x = M-tile(8), y = N-tile(4), z = expert(8) -> 256 blocks = 1/CU.
// LDS 128KB: buf0 {A 256x64 @0, B 256x64 @32K} buf1 @64K.
// Swizzle: chunk slot s of row r holds global chunk s ^ (r&7) (conflict-free).
// ---------------------------------------------------------------------------
__global__ __launch_bounds__(512, 2) void gemm_down(
    const _Float16* __restrict__ intHi, const _Float16* __restrict__ wd16,
    _Float16* __restrict__ eo) {
  __shared__ _Float16 lds[65536];  // 128 KB

  const int tid = threadIdx.x;
  const int wave = tid >> 6, lane = tid & 63;
  const int rowA0 = blockIdx.x * 256;
  const int colB0 = blockIdx.y * 256;
  const int e = blockIdx.z;

  const int sr = lane >> 3;             // row within 8-row wave stripe
  const int sc = lane & 7;              // LDS chunk slot
  const int gcol = (sc ^ sr) * 8;       // global k-offset (f16 elems)

  const int wm = wave >> 2;             // 0..1
  const int wn = wave & 3;              // 0..3
  const int fr = lane & 15;
  const int quad = lane >> 4;

  f32x4 acc[8][4];
#pragma unroll
  for (int i = 0; i < 8; ++i)
#pragma unroll
    for (int j = 0; j < 4; ++j) acc[i][j] = (f32x4){0.f, 0.f, 0.f, 0.f};

  const _Float16* aSrc = intHi + (size_t)e * T_TOK * I_DIM +
                         (size_t)(rowA0 + wave * 8 + sr) * I_DIM + gcol;
  const _Float16* bSrc = wd16 + ((size_t)e * H_DIM + colB0 + wave * 8 + sr) * I_DIM + gcol;
  char* ldsB = (char*)lds;
  char* ldsAw = ldsB + wave * 1024u;            // wave's 8-row stripe (8*128B)
  char* ldsBw = ldsAw + 32768u;                 // B tile at +32KB

  const int NT = I_DIM / 64;  // 32 K-tiles

  // prologue: stage tile 0 into buf0
#pragma unroll
  for (int s = 0; s < 4; ++s) {
    cp16(aSrc + (size_t)s * 64 * I_DIM, ldsAw + s * 8192u);
    cp16(bSrc + (size_t)s * 64 * I_DIM, ldsBw + s * 8192u);
  }
  __syncthreads();

  for (int t = 0; t < NT; ++t) {
    const int cur = t & 1;
    // issue-early: stage tile t+1 into the other buffer (front-loaded)
    if (t < NT - 1) {
      const unsigned nb = (unsigned)((cur ^ 1) * 65536u);
      const _Float16* aS = aSrc + (size_t)(t + 1) * 64;
      const _Float16* bS = bSrc + (size_t)(t + 1) * 64;
#pragma unroll
      for (int s = 0; s < 4; ++s) {
        cp16(aS + (size_t)s * 64 * I_DIM, ldsAw + nb + s * 8192u);
        cp16(bS + (size_t)s * 64 * I_DIM, ldsBw + nb + s * 8192u);
      }
    }
    // compute tile t from buf[cur]
    const int cb = cur * 32768;  // f16 elems
#pragma unroll
    for (int ks = 0; ks < 2; ++ks) {
      const int ksl = (ks * 4 + quad);
      f16x8 bh[4];
#pragma unroll
      for (int j = 0; j < 4; ++j) {
        const int row = wn * 64 + j * 16 + fr;
        bh[j] = *(const f16x8*)&lds[cb + 16384 + row * 64 + ((ksl ^ (fr & 7)) * 8)];
      }
      f16x8 ah[8];
#pragma unroll
      for (int i = 0; i < 8; ++i) {
        const int row = wm * 128 + i * 16 + fr;
        ah[i] = *(const f16x8*)&lds[cb + row * 64 + ((ksl ^ (fr & 7)) * 8)];
      }
      __builtin_amdgcn_s_setprio(1);
#pragma unroll
      for (int j = 0; j < 4; ++j)
#pragma unroll
        for (int i = 0; i < 8; ++i)
          acc[i][j] = __builtin_amdgcn_mfma_f32_16x16x32_f16(ah[i], bh[j], acc[i][j], 0, 0, 0);
      __builtin_amdgcn_s_setprio(0);
    }
    __syncthreads();  // vmcnt(0)+lgkmcnt(0)+barrier: t+1 landed, cur consumed
  }

  const int er = quad * 4;
  const int ec = lane & 15;
#pragma unroll
  for (int i = 0; i < 8; ++i)
#pragma unroll
    for (int j = 0; j < 4; ++j) {
      const int row = rowA0 + wm * 128 + i * 16 + er;
      const int col = colB0 + wn * 64 + j * 16 + ec;
#pragma unroll
      for (int r = 0; r < 4; ++r)
        eo[((size_t)e * T_TOK + row + r) * H_DIM + col] = (_Float16)acc[i][j][r];
    }
}

// ---------------------------------------------------------------------------
// Gram: gram36[p] = sum_j eo[a][j]*eo[b][j] for pairs a<=b.
// ---------------------------------------------------------------------------
__global__ __launch_bounds__(256) void gram_kernel(
    const _Float16* __restrict__ eo, float* __restrict__ gram) {
  float s[36];
#pragma unroll
  for (int p = 0; p < 36; ++p) s[p] = 0.f;
  const size_t total = (size_t)T_TOK * H_DIM;
  const size_t stride = (size_t)gridDim.x * 256;
  for (size_t j = (size_t)blockIdx.x * 256 + threadIdx.x; j < total; j += stride) {
    float v[NEXP];
#pragma unroll
    for (int e = 0; e < NEXP; ++e) v[e] = (float)eo[(size_t)e * total + j];
    int p = 0;
#pragma unroll
    for (int a = 0; a < NEXP; ++a)
#pragma unroll
      for (int b = a; b < NEXP; ++b) { s[p] += v[a] * v[b]; ++p; }
  }
#pragma unroll
  for (int p = 0; p < 36; ++p) {
    float v = s[p];
    for (int off = 32; off > 0; off >>= 1) v += __shfl_down(v, off);
    s[p] = v;
  }
  __shared__ float red[4][36];
  const int wave = threadIdx.x >> 6, lane = threadIdx.x & 63;
  if (lane == 0)
#pragma unroll
    for (int p = 0; p < 36; ++p) red[wave][p] = s[p];
  __syncthreads();
  if (threadIdx.x < 36) {
    float v = red[0][threadIdx.x] + red[1][threadIdx.x] + red[2][threadIdx.x] + red[3][threadIdx.x];
    atomicAdd(&gram[threadIdx.x], v);
  }
}

// ---------------------------------------------------------------------------
// Final (+fused sim): blocks [0,T_TOK) do out[t] = w0*eo[i0][t]+w1*eo[i1][t];
// block T_TOK (threads 0..63) computes the 8x8 similarity from gram36.
// Ordering safe: launched after gram_kernel completes (stream order).
// ---------------------------------------------------------------------------
__global__ __launch_bounds__(256) void final_kernel(
    const _Float16* __restrict__ eo, const int* __restrict__ topIdx,
    const float* __restrict__ topW, const float* __restrict__ gram,
    float* __restrict__ out) {
  const int t = blockIdx.x;
  if (t == T_TOK) {
    if (threadIdx.x < 64) {
      const int q = threadIdx.x;
      const int e1 = q >> 3, e2 = q & 7;
      int a = e1 < e2 ? e1 : e2;
      int b = e1 < e2 ? e2 : e1;
      const float g = gram[a * 8 - a * (a - 1) / 2 + (b - a)];
      const float sq1 = gram[e1 * 8 - e1 * (e1 - 1) / 2];
      const float sq2 = gram[e2 * 8 - e2 * (e2 - 1) / 2];
      float d2 = fmaxf(sq1 + sq2 - 2.f * g, 0.f);
      float dist = (e1 == e2) ? 0.f : sqrtf(d2);
      float dmax = dist;
      for (int off = 32; off > 0; off >>= 1) dmax = fmaxf(dmax, __shfl_xor(dmax, off));
      float sim = 1.f - dist / fmaxf(dmax, 1e-12f);
      if (e1 == e2) sim = 1.f;
      out[(size_t)T_TOK * H_DIM + q] = sim;
    }
    return;
  }
  const int c = threadIdx.x * 4;
  const int i0 = topIdx[2 * t], i1 = topIdx[2 * t + 1];
  const float w0 = topW[2 * t], w1 = topW[2 * t + 1];
  const size_t per = (size_t)T_TOK * H_DIM;
  f16x4 a = *(const f16x4*)&eo[(size_t)i0 * per + (size_t)t * H_DIM + c];
  f16x4 b = *(const f16x4*)&eo[(size_t)i1 * per + (size_t)t * H_DIM + c];
  float4 r;
  r.x = w0 * (float)a[0] + w1 * (float)b[0];
  r.y = w0 * (float)a[1] + w1 * (float)b[1];
  r.z = w0 * (float)a[2] + w1 * (float)b[2];
  r.w = w0 * (float)a[3] + w1 * (float)b[3];
  *(float4*)&out[(size_t)t * H_DIM + c] = r;
}

// ---------------------------------------------------------------------------
// Workspace layout, liveness-aliased base plan (needs 132 MiB + 48 KiB):
//  xHi @0 (4 MiB) | intHi @4 MiB (64 MiB)
//  gup16 @68 MiB (64 MiB, dead after gemm_gateup)
//  wd16 @68 MiB (32 MiB, born after gateup) -- UNLESS ws >= 169 MiB, in which
//    case wd16 @136 MiB and its cvt folds into prep (one fewer launch).
//  eo @100 MiB (32 MiB) | topIdx @132 MiB | topW +16K | gram +32K
// ---------------------------------------------------------------------------
extern "C" void kernel_launch(void* const* d_in, const int* in_sizes, int n_in,
                              void* d_out, int out_size, void* d_ws, size_t ws_size,
                              hipStream_t stream) {
  (void)in_sizes; (void)n_in; (void)out_size;
  const float* x   = (const float*)d_in[0];  // (2,1024,1024)
  const float* gw  = (const float*)d_in[1];  // (8,1024)
  const float* gup = (const float*)d_in[2];  // (8,4096,1024)
  const float* dwn = (const float*)d_in[3];  // (8,1024,2048)
  float* out = (float*)d_out;                // final (2M) ++ sim (64)

  char* ws = (char*)d_ws;
  const size_t MB = 1u << 20;
  _Float16* xHi    = (_Float16*)(ws + 0 * MB);
  _Float16* intHi  = (_Float16*)(ws + 4 * MB);
  _Float16* gup16  = (_Float16*)(ws + 68 * MB);
  _Float16* eo     = (_Float16*)(ws + 100 * MB);
  int*      topIdx = (int*)(ws + 132 * MB);
  float*    topW   = (float*)(ws + 132 * MB + 16384);
  float*    gram   = (float*)(ws + 132 * MB + 32768);

  const int doDwn = ws_size >= (size_t)169 * MB;
  _Float16* wd16 = doDwn ? (_Float16*)(ws + 136 * MB)
                         : (_Float16*)(ws + 68 * MB);  // aliases gup16

  // fused prep: router + gram-zero + cvt x + cvt gup [+ cvt dwn]
  const int prepBlocks = 512 + 2048 + 32768 + (doDwn ? 16384 : 0);
  prep_kernel<<<prepBlocks, 256, 0, stream>>>(
      x, xHi, gup, gup16, dwn, wd16, gw, topIdx, topW, gram);

  // gate+up fused: grid x=N (B-tiles XCD-co-located), y=M, z=E
  gemm_gateup<<<dim3(I_DIM / 128, T_TOK / 128, NEXP), 256, 0, stream>>>(
      xHi, gup16, intHi);

  // dwn -> f16 AFTER gateup only when wd16 must alias gup16's region
  if (!doDwn)
    cvt_f16_kernel<<<16384, 256, 0, stream>>>(dwn, wd16, NEXP * H_DIM * I_DIM);

  // down: 256x256 tiles, grid x=M (A-slabs XCD-co-located), y=N, z=E
  gemm_down<<<dim3(T_TOK / 256, H_DIM / 256, NEXP), 512, 0, stream>>>(
      intHi, wd16, eo);

  gram_kernel<<<2048, 256, 0, stream>>>(eo, gram);
  final_kernel<<<T_TOK + 1, 256, 0, stream>>>(eo, topIdx, topW, gram, out);
}

// Round 5
// 491.315 us; speedup vs baseline: 1.0454x; 1.0162x over previous
//
#include <hip/hip_runtime.h>
#include <math.h>

// Problem constants: B=2,S=1024 -> T=2048 tokens; H=1024; I=2048; E=8; TOP_K=2
#define T_TOK 2048
#define H_DIM 1024
#define I_DIM 2048
#define NEXP  8

typedef _Float16 f16x8 __attribute__((ext_vector_type(8)));
typedef _Float16 f16x4 __attribute__((ext_vector_type(4)));
typedef float    f32x4 __attribute__((ext_vector_type(4)));

// ---------------------------------------------------------------------------
// async 16B global->LDS copy. LDS dest = WAVE-UNIFORM base + lane*16.
// ---------------------------------------------------------------------------
__device__ __forceinline__ void cp16(const void* g, void* l) {
  __builtin_amdgcn_global_load_lds(
      (const __attribute__((address_space(1))) void*)g,
      (__attribute__((address_space(3))) void*)l, 16, 0, 0);
}

// ---------------------------------------------------------------------------
// fp32 -> f16 streaming convert (standalone; used for dwn when ws is small).
// ---------------------------------------------------------------------------
__global__ __launch_bounds__(256) void cvt_f16_kernel(
    const float* __restrict__ in, _Float16* __restrict__ hi, int n) {
  int i = (blockIdx.x * 256 + threadIdx.x) * 4;
  if (i >= n) return;
  float4 v = *(const float4*)(in + i);
  f16x4 hv = {(_Float16)v.x, (_Float16)v.y, (_Float16)v.z, (_Float16)v.w};
  *(f16x4*)(hi + i) = hv;
}

// ---------------------------------------------------------------------------
// PREP (fused): router + gram-zero + cvt x + cvt gup [+ cvt dwn if doDwn].
// Grid layout (256-thr blocks):
//   [0,512)            router: 4 tokens/block, one per wave; block 0 lanes<36
//                      also zero gram.
//   [512, 2560)        cvt x    (2M elems, 1024/block)
//   [2560, 35328)      cvt gup  (33.5M elems)
//   [35328, 35328+16K) cvt dwn  (16.8M elems) -- only when doDwn
// Router first: latency-bound blocks start early, hide under streaming cvt.
// ---------------------------------------------------------------------------
__global__ __launch_bounds__(256) void prep_kernel(
    const float* __restrict__ x, _Float16* __restrict__ xHi,
    const float* __restrict__ gup, _Float16* __restrict__ gup16,
    const float* __restrict__ dwn, _Float16* __restrict__ wd16,
    const float* __restrict__ gw,
    int* __restrict__ topIdx, float* __restrict__ topW,
    float* __restrict__ gram) {
  const int b = blockIdx.x;
  const int tid = threadIdx.x;

  if (b < 512) {
    // ---- router (one token per wave) + gram zero ----
    if (b == 0 && tid < 36) gram[tid] = 0.f;
    const int wave = tid >> 6, lane = tid & 63;
    const int t = b * 4 + wave;
    float p[NEXP];
#pragma unroll
    for (int e = 0; e < NEXP; ++e) p[e] = 0.f;
    const float* xr = x + (size_t)t * H_DIM;
    for (int h = lane; h < H_DIM; h += 64) {
      float xv = xr[h];
#pragma unroll
      for (int e = 0; e < NEXP; ++e) p[e] += xv * gw[e * H_DIM + h];
    }
#pragma unroll
    for (int e = 0; e < NEXP; ++e) {
      float v = p[e];
      for (int off = 32; off > 0; off >>= 1) v += __shfl_down(v, off);
      p[e] = v;
    }
    if (lane == 0) {
      float mx = p[0];
#pragma unroll
      for (int e = 1; e < NEXP; ++e) mx = fmaxf(mx, p[e]);
      float ex[NEXP], s = 0.f;
#pragma unroll
      for (int e = 0; e < NEXP; ++e) { ex[e] = expf(p[e] - mx); s += ex[e]; }
#pragma unroll
      for (int e = 0; e < NEXP; ++e) ex[e] /= s;
      int i0 = 0; float v0 = ex[0];
#pragma unroll
      for (int e = 1; e < NEXP; ++e) if (ex[e] > v0) { v0 = ex[e]; i0 = e; }
      int i1 = -1; float v1 = -1.f;
#pragma unroll
      for (int e = 0; e < NEXP; ++e) if (e != i0 && ex[e] > v1) { v1 = ex[e]; i1 = e; }
      float sum = fmaxf(v0 + v1, 1e-12f);
      topIdx[2 * t] = i0;  topIdx[2 * t + 1] = i1;
      topW[2 * t] = v0 / sum;  topW[2 * t + 1] = v1 / sum;
    }
    return;
  }

  // ---- streaming fp32 -> f16 converts ----
  int rb = b - 512;
  const float* src;
  _Float16* dst;
  if (rb < 2048) {
    src = x;  dst = xHi;
  } else if (rb < 2048 + 32768) {
    rb -= 2048;  src = gup;  dst = gup16;
  } else {
    rb -= (2048 + 32768);  src = dwn;  dst = wd16;
  }
  const size_t i = (size_t)rb * 1024 + (size_t)tid * 4;
  float4 v = *(const float4*)(src + i);
  f16x4 hv = {(_Float16)v.x, (_Float16)v.y, (_Float16)v.z, (_Float16)v.w};
  *(f16x4*)(dst + i) = hv;
}

// ---------------------------------------------------------------------------
// Fused gate+up GEMM, BK=64, all experts via gridDim.z, ALL-cp16 staging.
// inter[e][t][i] = silu(x@Wg^T) * (x@Wu^T), stored f16.
// GRID: x = N-tile, y = M-tile, z = expert. 128x128 tile, BK=64, 4 waves 2x2.
// LDS 48KB: A [0,16K) | Bg [16K,32K) | Bu [32K,48K).
// Swizzle: LDS chunk s of row r holds global k-chunk s ^ (r&7)  (conflict-free,
// measured SQ_LDS_BANK_CONFLICT = 0).
// ---------------------------------------------------------------------------
__global__ __launch_bounds__(256, 2) void gemm_gateup(
    const _Float16* __restrict__ xHi, const _Float16* __restrict__ gup16,
    _Float16* __restrict__ intHi) {
  __shared__ _Float16 lds[24576];  // 48 KB

  const int tid = threadIdx.x;
  const int wave = tid >> 6, lane = tid & 63;
  const int rowA0 = blockIdx.y * 128;  // M tile
  const int colB0 = blockIdx.x * 128;  // N tile within I
  const int e = blockIdx.z;

  // staging coords
  const int sr = lane >> 3;            // row within 8-row slice
  const int sc = lane & 7;             // LDS chunk
  const int gcol = (sc ^ sr) * 8;      // global k-offset (f16 elems), const/thread
  const int rbase = wave * 8 + sr;

  const int wm = wave >> 1, wn = wave & 1;
  const int fr = lane & 15;
  const int quad = lane >> 4;

  f32x4 accG[4][4], accU[4][4];
#pragma unroll
  for (int i = 0; i < 4; ++i)
#pragma unroll
    for (int j = 0; j < 4; ++j) {
      accG[i][j] = (f32x4){0.f, 0.f, 0.f, 0.f};
      accU[i][j] = (f32x4){0.f, 0.f, 0.f, 0.f};
    }

  const _Float16* gupG = gup16 + ((size_t)e * 2 * I_DIM + colB0) * H_DIM;
  const _Float16* gupU = gupG + (size_t)I_DIM * H_DIM;
  char* ldsB = (char*)lds;

  for (int k0 = 0; k0 < H_DIM; k0 += 64) {
    const int kcol = k0 + gcol;
#pragma unroll
    for (int i = 0; i < 4; ++i) {
      const int row = i * 32 + rbase;
      const unsigned dst = (unsigned)(i * 4096 + wave * 1024);
      cp16(xHi  + (size_t)(rowA0 + row) * H_DIM + kcol, ldsB + dst);
      cp16(gupG + (size_t)row * H_DIM + kcol, ldsB + 16384u + dst);
      cp16(gupU + (size_t)row * H_DIM + kcol, ldsB + 32768u + dst);
    }
    __syncthreads();

#pragma unroll
    for (int kk = 0; kk < 2; ++kk) {
      f16x8 ah[4];
#pragma unroll
      for (int i = 0; i < 4; ++i) {
        const int row = wm * 64 + i * 16 + fr;
        ah[i] = *(const f16x8*)&lds[row * 64 + (((kk * 4 + quad) ^ (fr & 7)) * 8)];
      }
#pragma unroll
      for (int j = 0; j < 4; ++j) {
        const int row = wn * 64 + j * 16 + fr;
        const int boff = row * 64 + (((kk * 4 + quad) ^ (fr & 7)) * 8);
        f16x8 bg = *(const f16x8*)&lds[8192 + boff];
        f16x8 bu = *(const f16x8*)&lds[16384 + boff];
#pragma unroll
        for (int i = 0; i < 4; ++i) {
          accG[i][j] = __builtin_amdgcn_mfma_f32_16x16x32_f16(ah[i], bg, accG[i][j], 0, 0, 0);
          accU[i][j] = __builtin_amdgcn_mfma_f32_16x16x32_f16(ah[i], bu, accU[i][j], 0, 0, 0);
        }
      }
    }
    __syncthreads();
  }

  // epilogue: C/D layout col=lane&15, row=quad*4+reg. inter = silu(g)*u -> f16
  const int er = quad * 4;
  const int ec = lane & 15;
#pragma unroll
  for (int i = 0; i < 4; ++i)
#pragma unroll
    for (int j = 0; j < 4; ++j) {
      const int row = rowA0 + wm * 64 + i * 16 + er;
      const int col = colB0 + wn * 64 + j * 16 + ec;
#pragma unroll
      for (int r = 0; r < 4; ++r) {
        float g = accG[i][j][r], u = accU[i][j][r];
        float val = g / (1.f + __expf(-g)) * u;
        intHi[((size_t)e * T_TOK + row + r) * I_DIM + col] = (_Float16)val;
      }
    }
}

// ---------------------------------------------------------------------------
// Down GEMM, gateup-shaped: 128M x 256N tile, BK=64, 8 waves (2M x 4N),
// single-buffered 48KB LDS, proven 2-barrier loop, all-cp16 staging.
// eo[e][t][h] (f16) = inter @ wd16^T.  M=T(2048), N=H(1024), K=I(2048).
// GRID: x = M-tile(16), y = N-tile(4), z = expert(8) -> 512 blocks = 2/CU.
// LDS 48KB: A 128x64 [0,16K) | B 256x64 [16K,48K).
// Staged in 64-row call-slices (8 waves x 8 rows x 8 chunks = 8KB/call):
//   A = 2 calls, B = 4 calls -> 6 cp16/thread per K-tile (= gateup ratio:
//   48KB staged per 256 block-MFMA).
// Swizzle: LDS chunk s of row r holds global chunk s ^ (r&7) (conflict-free,
// measured 0 in this family).
// ---------------------------------------------------------------------------
__global__ __launch_bounds__(512, 4) void gemm_down(
    const _Float16* __restrict__ intHi, const _Float16* __restrict__ wd16,
    _Float16* __restrict__ eo) {
  __shared__ _Float16 lds[24576];  // 48 KB

  const int tid = threadIdx.x;
  const int wave = tid >> 6, lane = tid & 63;
  const int rowA0 = blockIdx.x * 128;
  const int colB0 = blockIdx.y * 256;
  const int e = blockIdx.z;

  // staging coords
  const int sr = lane >> 3;             // row within 8-row wave stripe
  const int sc = lane & 7;              // LDS chunk slot
  const int gcol = (sc ^ sr) * 8;       // global k-offset (f16 elems)

  // compute coords: 8 waves = 2M x 4N; per-wave out 64 rows x 64 cols
  const int wm = wave >> 2;             // 0..1
  const int wn = wave & 3;              // 0..3
  const int fr = lane & 15;
  const int quad = lane >> 4;

  f32x4 acc[4][4];
#pragma unroll
  for (int i = 0; i < 4; ++i)
#pragma unroll
    for (int j = 0; j < 4; ++j) acc[i][j] = (f32x4){0.f, 0.f, 0.f, 0.f};

  // per-thread global staging bases (k advances by 64 elems per tile)
  const _Float16* aSrc = intHi + (size_t)e * T_TOK * I_DIM +
                         (size_t)(rowA0 + wave * 8 + sr) * I_DIM + gcol;
  const _Float16* bSrc = wd16 + ((size_t)e * H_DIM + colB0 + wave * 8 + sr) * I_DIM + gcol;
  char* ldsB = (char*)lds;

  for (int k0 = 0; k0 < I_DIM; k0 += 64) {
    // A: 2 call-slices of 64 rows; B: 4 call-slices of 64 rows
#pragma unroll
    for (int c = 0; c < 2; ++c)
      cp16(aSrc + (size_t)c * 64 * I_DIM + k0, ldsB + c * 8192u + wave * 1024u);
#pragma unroll
    for (int c = 0; c < 4; ++c)
      cp16(bSrc + (size_t)c * 64 * I_DIM + k0, ldsB + 16384u + c * 8192u + wave * 1024u);
    __syncthreads();

#pragma unroll
    for (int kk = 0; kk < 2; ++kk) {
      const int ksl = kk * 4 + quad;
      f16x8 ah[4];
#pragma unroll
      for (int i = 0; i < 4; ++i) {
        const int row = wm * 64 + i * 16 + fr;
        ah[i] = *(const f16x8*)&lds[row * 64 + ((ksl ^ (fr & 7)) * 8)];
      }
#pragma unroll
      for (int j = 0; j < 4; ++j) {
        const int row = wn * 64 + j * 16 + fr;
        f16x8 bh = *(const f16x8*)&lds[8192 + row * 64 + ((ksl ^ (fr & 7)) * 8)];
#pragma unroll
        for (int i = 0; i < 4; ++i)
          acc[i][j] = __builtin_amdgcn_mfma_f32_16x16x32_f16(ah[i], bh, acc[i][j], 0, 0, 0);
      }
    }
    __syncthreads();
  }

  // epilogue: C/D layout col=lane&15, row=quad*4+reg
  const int er = quad * 4;
  const int ec = lane & 15;
#pragma unroll
  for (int i = 0; i < 4; ++i)
#pragma unroll
    for (int j = 0; j < 4; ++j) {
      const int row = rowA0 + wm * 64 + i * 16 + er;
      const int col = colB0 + wn * 64 + j * 16 + ec;
#pragma unroll
      for (int r = 0; r < 4; ++r)
        eo[((size_t)e * T_TOK + row + r) * H_DIM + col] = (_Float16)acc[i][j][r];
    }
}

// ---------------------------------------------------------------------------
// Gram: gram36[p] = sum_j eo[a][j]*eo[b][j] for pairs a<=b.
// Vectorized: each thread handles 8 contiguous f16 per expert (f16x8 loads).
// Grid 1024 x 256 thr x 8 elems = exactly T*H in one pass.
// ---------------------------------------------------------------------------
__global__ __launch_bounds__(256) void gram_kernel(
    const _Float16* __restrict__ eo, float* __restrict__ gram) {
  float s[36];
#pragma unroll
  for (int p = 0; p < 36; ++p) s[p] = 0.f;
  const size_t total = (size_t)T_TOK * H_DIM;
  const size_t stride = (size_t)gridDim.x * 256 * 8;
  for (size_t j = ((size_t)blockIdx.x * 256 + threadIdx.x) * 8; j < total; j += stride) {
    f16x8 ve[NEXP];
#pragma unroll
    for (int e = 0; e < NEXP; ++e) ve[e] = *(const f16x8*)&eo[(size_t)e * total + j];
#pragma unroll
    for (int k = 0; k < 8; ++k) {
      float v[NEXP];
#pragma unroll
      for (int e = 0; e < NEXP; ++e) v[e] = (float)ve[e][k];
      int p = 0;
#pragma unroll
      for (int a = 0; a < NEXP; ++a)
#pragma unroll
        for (int b = a; b < NEXP; ++b) { s[p] += v[a] * v[b]; ++p; }
    }
  }
#pragma unroll
  for (int p = 0; p < 36; ++p) {
    float v = s[p];
    for (int off = 32; off > 0; off >>= 1) v += __shfl_down(v, off);
    s[p] = v;
  }
  __shared__ float red[4][36];
  const int wave = threadIdx.x >> 6, lane = threadIdx.x & 63;
  if (lane == 0)
#pragma unroll
    for (int p = 0; p < 36; ++p) red[wave][p] = s[p];
  __syncthreads();
  if (threadIdx.x < 36) {
    float v = red[0][threadIdx.x] + red[1][threadIdx.x] + red[2][threadIdx.x] + red[3][threadIdx.x];
    atomicAdd(&gram[threadIdx.x], v);
  }
}

// ---------------------------------------------------------------------------
// Final (+fused sim): blocks [0,T_TOK) do out[t] = w0*eo[i0][t]+w1*eo[i1][t];
// block T_TOK (threads 0..63) computes the 8x8 similarity from gram36.
// Ordering safe: launched after gram_kernel completes (stream order).
// ---------------------------------------------------------------------------
__global__ __launch_bounds__(256) void final_kernel(
    const _Float16* __restrict__ eo, const int* __restrict__ topIdx,
    const float* __restrict__ topW, const float* __restrict__ gram,
    float* __restrict__ out) {
  const int t = blockIdx.x;
  if (t == T_TOK) {
    if (threadIdx.x < 64) {
      const int q = threadIdx.x;
      const int e1 = q >> 3, e2 = q & 7;
      int a = e1 < e2 ? e1 : e2;
      int b = e1 < e2 ? e2 : e1;
      const float g = gram[a * 8 - a * (a - 1) / 2 + (b - a)];
      const float sq1 = gram[e1 * 8 - e1 * (e1 - 1) / 2];
      const float sq2 = gram[e2 * 8 - e2 * (e2 - 1) / 2];
      float d2 = fmaxf(sq1 + sq2 - 2.f * g, 0.f);
      float dist = (e1 == e2) ? 0.f : sqrtf(d2);
      float dmax = dist;
      for (int off = 32; off > 0; off >>= 1) dmax = fmaxf(dmax, __shfl_xor(dmax, off));
      float sim = 1.f - dist / fmaxf(dmax, 1e-12f);
      if (e1 == e2) sim = 1.f;
      out[(size_t)T_TOK * H_DIM + q] = sim;
    }
    return;
  }
  const int c = threadIdx.x * 4;
  const int i0 = topIdx[2 * t], i1 = topIdx[2 * t + 1];
  const float w0 = topW[2 * t], w1 = topW[2 * t + 1];
  const size_t per = (size_t)T_TOK * H_DIM;
  f16x4 a = *(const f16x4*)&eo[(size_t)i0 * per + (size_t)t * H_DIM + c];
  f16x4 b = *(const f16x4*)&eo[(size_t)i1 * per + (size_t)t * H_DIM + c];
  float4 r;
  r.x = w0 * (float)a[0] + w1 * (float)b[0];
  r.y = w0 * (float)a[1] + w1 * (float)b[1];
  r.z = w0 * (float)a[2] + w1 * (float)b[2];
  r.w = w0 * (float)a[3] + w1 * (float)b[3];
  *(float4*)&out[(size_t)t * H_DIM + c] = r;
}

// ---------------------------------------------------------------------------
// Workspace layout, liveness-aliased base plan (needs 132 MiB + 48 KiB):
//  xHi @0 (4 MiB) | intHi @4 MiB (64 MiB)
//  gup16 @68 MiB (64 MiB, dead after gemm_gateup)
//  wd16 @68 MiB (32 MiB, born after gateup) -- UNLESS ws >= 169 MiB, in which
//    case wd16 @136 MiB and its cvt folds into prep (one fewer launch).
//  eo @100 MiB (32 MiB) | topIdx @132 MiB | topW +16K | gram +32K
// ---------------------------------------------------------------------------
extern "C" void kernel_launch(void* const* d_in, const int* in_sizes, int n_in,
                              void* d_out, int out_size, void* d_ws, size_t ws_size,
                              hipStream_t stream) {
  (void)in_sizes; (void)n_in; (void)out_size;
  const float* x   = (const float*)d_in[0];  // (2,1024,1024)
  const float* gw  = (const float*)d_in[1];  // (8,1024)
  const float* gup = (const float*)d_in[2];  // (8,4096,1024)
  const float* dwn = (const float*)d_in[3];  // (8,1024,2048)
  float* out = (float*)d_out;                // final (2M) ++ sim (64)

  char* ws = (char*)d_ws;
  const size_t MB = 1u << 20;
  _Float16* xHi    = (_Float16*)(ws + 0 * MB);
  _Float16* intHi  = (_Float16*)(ws + 4 * MB);
  _Float16* gup16  = (_Float16*)(ws + 68 * MB);
  _Float16* eo     = (_Float16*)(ws + 100 * MB);
  int*      topIdx = (int*)(ws + 132 * MB);
  float*    topW   = (float*)(ws + 132 * MB + 16384);
  float*    gram   = (float*)(ws + 132 * MB + 32768);

  const int doDwn = ws_size >= (size_t)169 * MB;
  _Float16* wd16 = doDwn ? (_Float16*)(ws + 136 * MB)
                         : (_Float16*)(ws + 68 * MB);  // aliases gup16

  // fused prep: router + gram-zero + cvt x + cvt gup [+ cvt dwn]
  const int prepBlocks = 512 + 2048 + 32768 + (doDwn ? 16384 : 0);
  prep_kernel<<<prepBlocks, 256, 0, stream>>>(
      x, xHi, gup, gup16, dwn, wd16, gw, topIdx, topW, gram);

  // gate+up fused: grid x=N (B-tiles XCD-co-located), y=M, z=E
  gemm_gateup<<<dim3(I_DIM / 128, T_TOK / 128, NEXP), 256, 0, stream>>>(
      xHi, gup16, intHi);

  // dwn -> f16 AFTER gateup only when wd16 must alias gup16's region
  if (!doDwn)
    cvt_f16_kernel<<<16384, 256, 0, stream>>>(dwn, wd16, NEXP * H_DIM * I_DIM);

  // down: 128x256 tiles, grid x=M, y=N, z=E -> 512 blocks = 2/CU
  gemm_down<<<dim3(T_TOK / 128, H_DIM / 256, NEXP), 512, 0, stream>>>(
      intHi, wd16, eo);

  gram_kernel<<<1024, 256, 0, stream>>>(eo, gram);
  final_kernel<<<T_TOK + 1, 256, 0, stream>>>(eo, topIdx, topW, gram, out);
}